// Round 1
// baseline (518.978 us; speedup 1.0000x reference)
//
#include <hip/hip_runtime.h>
#include <math.h>

// GCN 2-layer on [N,1] input collapses to scalar passes:
//   deg[c]  = 1 + #(col==c)                       (self-loop included)
//   dis[i]  = 1/sqrt(deg[i])
//   s[c]    = dis[c]^2*x[c] + sum_e dis[row]*dis[c]*x[row]   (layer-1 agg, scalar)
//   alpha   = sum_f W1[f]*W2[f];  beta = sum_f b1[f]*W2[f]
//   hw[i]   = alpha*s[i] + beta                   (both dense layers fused)
//   out[c]  = dis[c]^2*hw[c] + sum_e dis[row]*dis[c]*hw[row] + b2

static __device__ __forceinline__ int gid() {
    return blockIdx.x * blockDim.x + threadIdx.x;
}

__global__ void k_init_deg(float* __restrict__ deg, int n) {
    int i = gid();
    if (i < n) deg[i] = 1.0f;  // self-loop contribution
}

__global__ void k_deg(const int* __restrict__ col, float* __restrict__ deg, int E) {
    int i = gid();
    int base = i * 4;
    if (base + 4 <= E) {
        int4 c = *reinterpret_cast<const int4*>(col + base);
        atomicAdd(&deg[c.x], 1.0f);
        atomicAdd(&deg[c.y], 1.0f);
        atomicAdd(&deg[c.z], 1.0f);
        atomicAdd(&deg[c.w], 1.0f);
    } else {
        for (int j = base; j < E; ++j) atomicAdd(&deg[col[j]], 1.0f);
    }
}

// deg -> dis (in place), and init s with the self-loop term dis^2 * x
__global__ void k_dis_init_s(const float* __restrict__ x, float* __restrict__ deg_dis,
                             float* __restrict__ s, int n) {
    int i = gid();
    if (i < n) {
        float dis = 1.0f / sqrtf(deg_dis[i]);
        deg_dis[i] = dis;
        s[i] = dis * dis * x[i];
    }
}

__global__ void k_scatter_s(const int* __restrict__ ei, const float* __restrict__ dis,
                            const float* __restrict__ x, float* __restrict__ s,
                            int E) {
    int i = gid();
    int base = i * 4;
    const int* rowp = ei;
    const int* colp = ei + E;
    if (base + 4 <= E) {
        int4 r = *reinterpret_cast<const int4*>(rowp + base);
        int4 c = *reinterpret_cast<const int4*>(colp + base);
        atomicAdd(&s[c.x], dis[r.x] * dis[c.x] * x[r.x]);
        atomicAdd(&s[c.y], dis[r.y] * dis[c.y] * x[r.y]);
        atomicAdd(&s[c.z], dis[r.z] * dis[c.z] * x[r.z]);
        atomicAdd(&s[c.w], dis[r.w] * dis[c.w] * x[r.w]);
    } else {
        for (int j = base; j < E; ++j) {
            int r = rowp[j], c = colp[j];
            atomicAdd(&s[c], dis[r] * dis[c] * x[r]);
        }
    }
}

// alpha = W1 . W2, beta = b1 . W2  (HIDDEN = 64 = one wave)
__global__ void k_ab(const float* __restrict__ W1, const float* __restrict__ b1,
                     const float* __restrict__ W2, float* __restrict__ ab, int hidden) {
    int t = threadIdx.x;
    float w2 = (t < hidden) ? W2[t] : 0.0f;
    float a = (t < hidden) ? W1[t] * w2 : 0.0f;
    float b = (t < hidden) ? b1[t] * w2 : 0.0f;
    for (int o = 32; o; o >>= 1) {
        a += __shfl_down(a, o, 64);
        b += __shfl_down(b, o, 64);
    }
    if (t == 0) { ab[0] = a; ab[1] = b; }
}

// hw = alpha*s + beta; out init with self-loop term + bias b2
__global__ void k_hw_init_out(const float* __restrict__ s, const float* __restrict__ dis,
                              const float* __restrict__ ab, const float* __restrict__ b2,
                              float* __restrict__ hw, float* __restrict__ out, int n) {
    int i = gid();
    if (i < n) {
        float h = ab[0] * s[i] + ab[1];
        hw[i] = h;
        float d = dis[i];
        out[i] = d * d * h + b2[0];
    }
}

__global__ void k_scatter_out(const int* __restrict__ ei, const float* __restrict__ dis,
                              const float* __restrict__ hw, float* __restrict__ out,
                              int E) {
    int i = gid();
    int base = i * 4;
    const int* rowp = ei;
    const int* colp = ei + E;
    if (base + 4 <= E) {
        int4 r = *reinterpret_cast<const int4*>(rowp + base);
        int4 c = *reinterpret_cast<const int4*>(colp + base);
        atomicAdd(&out[c.x], dis[r.x] * dis[c.x] * hw[r.x]);
        atomicAdd(&out[c.y], dis[r.y] * dis[c.y] * hw[r.y]);
        atomicAdd(&out[c.z], dis[r.z] * dis[c.z] * hw[r.z]);
        atomicAdd(&out[c.w], dis[r.w] * dis[c.w] * hw[r.w]);
    } else {
        for (int j = base; j < E; ++j) {
            int r = rowp[j], c = colp[j];
            atomicAdd(&out[c], dis[r] * dis[c] * hw[r]);
        }
    }
}

extern "C" void kernel_launch(void* const* d_in, const int* in_sizes, int n_in,
                              void* d_out, int out_size, void* d_ws, size_t ws_size,
                              hipStream_t stream) {
    const float* x  = (const float*)d_in[0];
    const int*   ei = (const int*)d_in[1];
    const float* W1 = (const float*)d_in[2];
    const float* b1 = (const float*)d_in[3];
    const float* W2 = (const float*)d_in[4];
    const float* b2 = (const float*)d_in[5];
    float* out = (float*)d_out;

    const int N = in_sizes[0];       // 100000 nodes
    const int E = in_sizes[1] / 2;   // 3200000 edges
    const int H = in_sizes[2];       // 64 hidden

    float* ws = (float*)d_ws;
    float* deg_dis = ws;             // [N] degree, then dis in-place
    float* s       = ws + N;         // [N]
    float* hw      = ws + 2 * N;     // [N]
    float* ab      = ws + 3 * N;     // [2]

    const int BLK = 256;
    const int nodeGrid = (N + BLK - 1) / BLK;
    const int e4 = (E + 3) / 4;
    const int edgeGrid = (e4 + BLK - 1) / BLK;

    k_init_deg<<<nodeGrid, BLK, 0, stream>>>(deg_dis, N);
    k_deg<<<edgeGrid, BLK, 0, stream>>>(ei + E, deg_dis, E);
    k_dis_init_s<<<nodeGrid, BLK, 0, stream>>>(x, deg_dis, s, N);
    k_scatter_s<<<edgeGrid, BLK, 0, stream>>>(ei, deg_dis, x, s, E);
    k_ab<<<1, 64, 0, stream>>>(W1, b1, W2, ab, H);
    k_hw_init_out<<<nodeGrid, BLK, 0, stream>>>(s, deg_dis, ab, b2, hw, out, N);
    k_scatter_out<<<edgeGrid, BLK, 0, stream>>>(ei, deg_dis, hw, out, E);
}

// Round 2
// 491.182 us; speedup vs baseline: 1.0566x; 1.0566x over previous
//
#include <hip/hip_runtime.h>
#include <math.h>

// GCN 2-layer on [N,1] collapses to scalar passes (see round-0 derivation):
//   dis[i] = 1/sqrt(1 + indeg[i]);  g[i] = dis[i]*x[i]
//   s[c]   = dis[c]*(g[c] + sum_{e->c} g[row_e])
//   h[i]   = alpha*s[i] + beta   (alpha = W1.W2, beta = b1.W2)
//   g2[i]  = dis[i]*h[i]
//   out[c] = dis[c]*(g2[c] + sum_{e->c} g2[row_e]) + b2
//
// Scatter strategy: device-scope atomicAdd is serviced at the cross-XCD
// coherence point (rocprof: WRITE_SIZE = 32B/atomic, ~20G atomics/s cap).
// Instead: 8 per-XCD replica accumulators + local-L2 atomics (inline asm
// global_atomic_add_f32 WITHOUT sc1), reduced O(N) between passes.

#define NXCD 8

static __device__ __forceinline__ unsigned xcc_id() {
    unsigned x;
    asm volatile("s_getreg_b32 %0, hwreg(HW_REG_XCC_ID)" : "=s"(x));
    return x & 7u;
}

// Atomic add serviced at the local XCD's L2 (no sc0/sc1 -> not cross-XCD
// coherent; correct only because each replica is touched by one XCD).
static __device__ __forceinline__ void atomic_add_l2(float* p, float v) {
    asm volatile("global_atomic_add_f32 %0, %1, off" :: "v"(p), "v"(v) : "memory");
}

static __device__ __forceinline__ int gid() {
    return blockIdx.x * blockDim.x + threadIdx.x;
}

__global__ void k_zero(float* __restrict__ p, int n4) {
    int i = gid();
    if (i < n4) reinterpret_cast<float4*>(p)[i] = make_float4(0.f, 0.f, 0.f, 0.f);
}

// alpha = W1 . W2, beta = b1 . W2  (HIDDEN = 64 = one wave)
__global__ void k_ab(const float* __restrict__ W1, const float* __restrict__ b1,
                     const float* __restrict__ W2, float* __restrict__ ab, int hidden) {
    int t = threadIdx.x;
    float w2 = (t < hidden) ? W2[t] : 0.0f;
    float a = (t < hidden) ? W1[t] * w2 : 0.0f;
    float b = (t < hidden) ? b1[t] * w2 : 0.0f;
    for (int o = 32; o; o >>= 1) {
        a += __shfl_down(a, o);
        b += __shfl_down(b, o);
    }
    if (t == 0) { ab[0] = a; ab[1] = b; }
}

// indeg counts into per-XCD replica
__global__ void k_deg(const int* __restrict__ col, float* __restrict__ part,
                      int E, int N) {
    float* my = part + (size_t)xcc_id() * N;
    int base = gid() * 4;
    if (base + 4 <= E) {
        int4 c = *reinterpret_cast<const int4*>(col + base);
        atomic_add_l2(my + c.x, 1.0f);
        atomic_add_l2(my + c.y, 1.0f);
        atomic_add_l2(my + c.z, 1.0f);
        atomic_add_l2(my + c.w, 1.0f);
    } else {
        for (int j = base; j < E; ++j) atomic_add_l2(my + col[j], 1.0f);
    }
}

// reduce replicas -> deg, clear replicas, compute dis and g = dis*x
__global__ void k_reduce_disg(const float* __restrict__ x, float* __restrict__ part,
                              float* __restrict__ dis, float* __restrict__ g, int N) {
    int i = gid();
    if (i >= N) return;
    float t = 1.0f;  // self-loop
    #pragma unroll
    for (int k = 0; k < NXCD; ++k) { t += part[k * N + i]; part[k * N + i] = 0.0f; }
    float d = rsqrtf(t);
    dis[i] = d;
    g[i] = d * x[i];
}

// scatter values val[row] into per-XCD replica at col
__global__ void k_scatter(const int* __restrict__ ei, const float* __restrict__ val,
                          float* __restrict__ part, int E, int N) {
    float* my = part + (size_t)xcc_id() * N;
    const int* rowp = ei;
    const int* colp = ei + E;
    int base = gid() * 4;
    if (base + 4 <= E) {
        int4 r = *reinterpret_cast<const int4*>(rowp + base);
        int4 c = *reinterpret_cast<const int4*>(colp + base);
        atomic_add_l2(my + c.x, val[r.x]);
        atomic_add_l2(my + c.y, val[r.y]);
        atomic_add_l2(my + c.z, val[r.z]);
        atomic_add_l2(my + c.w, val[r.w]);
    } else {
        for (int j = base; j < E; ++j) atomic_add_l2(my + colp[j], val[rowp[j]]);
    }
}

// reduce replicas -> s, clear, fuse both dense layers, emit g2 = dis*h
__global__ void k_reduce_s(const float* __restrict__ g, const float* __restrict__ dis,
                           const float* __restrict__ ab, float* __restrict__ part,
                           float* __restrict__ g2, int N) {
    int i = gid();
    if (i >= N) return;
    float t = g[i];  // self-loop term dis*(g[i] + sum)
    #pragma unroll
    for (int k = 0; k < NXCD; ++k) { t += part[k * N + i]; part[k * N + i] = 0.0f; }
    float s = dis[i] * t;
    float h = ab[0] * s + ab[1];
    g2[i] = dis[i] * h;
}

// reduce replicas -> out
__global__ void k_reduce_out(const float* __restrict__ g2, const float* __restrict__ dis,
                             const float* __restrict__ b2, const float* __restrict__ part,
                             float* __restrict__ out, int N) {
    int i = gid();
    if (i >= N) return;
    float t = g2[i];
    #pragma unroll
    for (int k = 0; k < NXCD; ++k) t += part[k * N + i];
    out[i] = dis[i] * t + b2[0];
}

extern "C" void kernel_launch(void* const* d_in, const int* in_sizes, int n_in,
                              void* d_out, int out_size, void* d_ws, size_t ws_size,
                              hipStream_t stream) {
    const float* x  = (const float*)d_in[0];
    const int*   ei = (const int*)d_in[1];
    const float* W1 = (const float*)d_in[2];
    const float* b1 = (const float*)d_in[3];
    const float* W2 = (const float*)d_in[4];
    const float* b2 = (const float*)d_in[5];
    float* out = (float*)d_out;

    const int N = in_sizes[0];       // 100000
    const int E = in_sizes[1] / 2;   // 3200000
    const int H = in_sizes[2];       // 64

    float* ws   = (float*)d_ws;
    float* part = ws;                     // [8*N] per-XCD replicas
    float* dis  = ws + (size_t)NXCD * N;  // [N]
    float* g    = dis + N;                // [N]
    float* g2   = g + N;                  // [N]
    float* ab   = g2 + N;                 // [2]

    const int BLK = 256;
    const int nodeGrid = (N + BLK - 1) / BLK;
    const int e4 = (E + 3) / 4;
    const int edgeGrid = (e4 + BLK - 1) / BLK;
    const int z4 = (NXCD * N) / 4;
    const int zeroGrid = (z4 + BLK - 1) / BLK;

    k_zero<<<zeroGrid, BLK, 0, stream>>>(part, z4);
    k_ab<<<1, 64, 0, stream>>>(W1, b1, W2, ab, H);
    k_deg<<<edgeGrid, BLK, 0, stream>>>(ei + E, part, E, N);
    k_reduce_disg<<<nodeGrid, BLK, 0, stream>>>(x, part, dis, g, N);
    k_scatter<<<edgeGrid, BLK, 0, stream>>>(ei, g, part, E, N);
    k_reduce_s<<<nodeGrid, BLK, 0, stream>>>(g, dis, ab, part, g2, N);
    k_scatter<<<edgeGrid, BLK, 0, stream>>>(ei, g2, part, E, N);
    k_reduce_out<<<nodeGrid, BLK, 0, stream>>>(g2, dis, b2, part, out, N);
}

// Round 3
// 145.840 us; speedup vs baseline: 3.5586x; 3.3680x over previous
//
#include <hip/hip_runtime.h>
#include <math.h>

// GCN 2-layer on [N,1] collapses to scalar passes:
//   dis[i] = 1/sqrt(1 + indeg[i]);  g[i] = dis[i]*x[i]
//   s[c]   = dis[c]*(g[c] + sum_{e->c} g[row_e])
//   h[i]   = alpha*s[i] + beta   (alpha = W1.W2, beta = b1.W2)
//   g2[i]  = dis[i]*h[i]
//   out[c] = dis[c]*(g2[c] + sum_{e->c} g2[row_e]) + b2
//
// Round-2 finding: gfx950 global atomics are ~20G/s flat (write-through,
// 32B HBM write each) regardless of scope bits. So: counting-sort edges by
// destination chunk ONCE (only ~400K global atomics for reservations), then
// all per-edge accumulation is LDS atomics + coalesced stores.

#define CHUNK 128
#define CHUNK_SHIFT 7
#define NBMAX 1024
#define PACK_SHIFT 20          // low 20 bits: row; high bits: col within chunk

static __device__ __forceinline__ int gid() {
    return blockIdx.x * blockDim.x + threadIdx.x;
}

__global__ void k_zero_i(int* __restrict__ p, int n) {
    int i = gid();
    if (i < n) p[i] = 0;
}

__global__ void k_zero_f(float* __restrict__ p, int n) {
    int i = gid();
    if (i < n) p[i] = 0.0f;
}

// alpha = W1 . W2, beta = b1 . W2  (HIDDEN = 64 = one wave)
__global__ void k_ab(const float* __restrict__ W1, const float* __restrict__ b1,
                     const float* __restrict__ W2, float* __restrict__ ab, int hidden) {
    int t = threadIdx.x;
    float w2 = (t < hidden) ? W2[t] : 0.0f;
    float a = (t < hidden) ? W1[t] * w2 : 0.0f;
    float b = (t < hidden) ? b1[t] * w2 : 0.0f;
    for (int o = 32; o; o >>= 1) {
        a += __shfl_down(a, o);
        b += __shfl_down(b, o);
    }
    if (t == 0) { ab[0] = a; ab[1] = b; }
}

// ---- sort pipeline -------------------------------------------------------

__global__ void k_hist(const int* __restrict__ col, int E, int NB,
                       int* __restrict__ gcount) {
    __shared__ int cnt[NBMAX];
    for (int t = threadIdx.x; t < NB; t += blockDim.x) cnt[t] = 0;
    __syncthreads();
    int stride = gridDim.x * blockDim.x;
    for (int j = gid(); j < E; j += stride)
        atomicAdd(&cnt[col[j] >> CHUNK_SHIFT], 1);
    __syncthreads();
    for (int t = threadIdx.x; t < NB; t += blockDim.x)
        if (cnt[t]) atomicAdd(&gcount[t], cnt[t]);
}

// single block, NBMAX threads: exclusive scan of gcount -> base, cursor
__global__ void k_scan(const int* __restrict__ gcount, int* __restrict__ base,
                       int* __restrict__ cursor, int NB, int E) {
    __shared__ int sh[NBMAX];
    int t = threadIdx.x;
    int v0 = (t < NB) ? gcount[t] : 0;
    sh[t] = v0;
    __syncthreads();
    for (int off = 1; off < NBMAX; off <<= 1) {
        int v = sh[t];
        int add = (t >= off) ? sh[t - off] : 0;
        __syncthreads();
        sh[t] = v + add;
        __syncthreads();
    }
    int excl = sh[t] - v0;
    if (t < NB) { base[t] = excl; cursor[t] = excl; }
    if (t == 0) base[NB] = E;
}

__global__ void k_place(const int* __restrict__ row, const int* __restrict__ col,
                        int E, int NB, int* __restrict__ cursor,
                        unsigned* __restrict__ sorted) {
    __shared__ int cnt[NBMAX];
    __shared__ int bbase[NBMAX];
    int per = (E + gridDim.x - 1) / gridDim.x;
    int lo = blockIdx.x * per;
    int hi = min(E, lo + per);
    for (int t = threadIdx.x; t < NB; t += blockDim.x) cnt[t] = 0;
    __syncthreads();
    for (int j = lo + threadIdx.x; j < hi; j += blockDim.x)
        atomicAdd(&cnt[col[j] >> CHUNK_SHIFT], 1);
    __syncthreads();
    for (int t = threadIdx.x; t < NB; t += blockDim.x) {
        int c = cnt[t];
        bbase[t] = c ? atomicAdd(&cursor[t], c) : 0;
        cnt[t] = 0;
    }
    __syncthreads();
    for (int j = lo + threadIdx.x; j < hi; j += blockDim.x) {
        int c = col[j];
        int b = c >> CHUNK_SHIFT;
        int off = atomicAdd(&cnt[b], 1);
        unsigned p = (unsigned)row[j] | ((unsigned)(c & (CHUNK - 1)) << PACK_SHIFT);
        sorted[bbase[b] + off] = p;
    }
}

// one block per bucket; val==nullptr means accumulate 1.0 (degree pass)
__global__ void k_acc(const unsigned* __restrict__ sorted, const int* __restrict__ base,
                      const float* __restrict__ val, float* __restrict__ outacc,
                      int N, int NB) {
    __shared__ float acc[CHUNK];
    int b = blockIdx.x;
    if (threadIdx.x < CHUNK) acc[threadIdx.x] = 0.0f;
    __syncthreads();
    int lo = base[b], hi = base[b + 1];
    for (int j = lo + threadIdx.x; j < hi; j += blockDim.x) {
        unsigned p = sorted[j];
        float v = val ? val[p & ((1u << PACK_SHIFT) - 1)] : 1.0f;
        atomicAdd(&acc[p >> PACK_SHIFT], v);
    }
    __syncthreads();
    int node = b * CHUNK + threadIdx.x;
    if (threadIdx.x < CHUNK && node < N) outacc[node] = acc[threadIdx.x];
}

// ---- node-wise passes ----------------------------------------------------

__global__ void k_node1(const float* __restrict__ x, const float* __restrict__ degsum,
                        float* __restrict__ dis, float* __restrict__ g, int N) {
    int i = gid();
    if (i < N) {
        float d = rsqrtf(1.0f + degsum[i]);
        dis[i] = d;
        g[i] = d * x[i];
    }
}

__global__ void k_node2(const float* __restrict__ g, const float* __restrict__ dis,
                        const float* __restrict__ ab, const float* __restrict__ sum1,
                        float* __restrict__ g2, int N) {
    int i = gid();
    if (i < N) {
        float s = dis[i] * (g[i] + sum1[i]);
        float h = ab[0] * s + ab[1];
        g2[i] = dis[i] * h;
    }
}

__global__ void k_node3(const float* __restrict__ g2, const float* __restrict__ dis,
                        const float* __restrict__ b2, const float* __restrict__ sum2,
                        float* __restrict__ out, int N) {
    int i = gid();
    if (i < N) out[i] = dis[i] * (g2[i] + sum2[i]) + b2[0];
}

// ---- fallback (plain device atomics, known-correct) ----------------------

__global__ void k_deg_fb(const int* __restrict__ col, float* __restrict__ t, int E) {
    int i = gid();
    if (i < E) atomicAdd(&t[col[i]], 1.0f);
}

__global__ void k_scat_fb(const int* __restrict__ ei, const float* __restrict__ val,
                          float* __restrict__ t, int E) {
    int i = gid();
    if (i < E) atomicAdd(&t[ei[E + i]], val[ei[i]]);
}

extern "C" void kernel_launch(void* const* d_in, const int* in_sizes, int n_in,
                              void* d_out, int out_size, void* d_ws, size_t ws_size,
                              hipStream_t stream) {
    const float* x  = (const float*)d_in[0];
    const int*   ei = (const int*)d_in[1];
    const float* W1 = (const float*)d_in[2];
    const float* b1 = (const float*)d_in[3];
    const float* W2 = (const float*)d_in[4];
    const float* b2 = (const float*)d_in[5];
    float* out = (float*)d_out;

    const int N = in_sizes[0];       // 100000
    const int E = in_sizes[1] / 2;   // 3200000
    const int H = in_sizes[2];       // 64
    const int NB = (N + CHUNK - 1) >> CHUNK_SHIFT;

    const int BLK = 256;
    const int nodeGrid = (N + BLK - 1) / BLK;

    // workspace layout
    char* w = (char*)d_ws;
    unsigned* sorted = (unsigned*)w;             w += (size_t)E * 4;
    float* dis = (float*)w;                      w += (size_t)N * 4;
    float* g   = (float*)w;                      w += (size_t)N * 4;
    float* g2  = (float*)w;                      w += (size_t)N * 4;
    float* tmp = (float*)w;                      w += (size_t)N * 4;
    int* gcount = (int*)w;                       w += (size_t)NBMAX * 4;
    int* base   = (int*)w;                       w += (size_t)(NBMAX + 1) * 4;
    int* cursor = (int*)w;                       w += (size_t)NBMAX * 4;
    float* ab   = (float*)w;                     w += 2 * 4;
    size_t needed = (size_t)(w - (char*)d_ws);

    if (NB <= NBMAX && ws_size >= needed) {
        // sort once
        k_zero_i<<<(NBMAX + BLK - 1) / BLK, BLK, 0, stream>>>(gcount, NBMAX);
        k_ab<<<1, 64, 0, stream>>>(W1, b1, W2, ab, H);
        k_hist<<<256, 256, 0, stream>>>(ei + E, E, NB, gcount);
        k_scan<<<1, NBMAX, 0, stream>>>(gcount, base, cursor, NB, E);
        k_place<<<256, 512, 0, stream>>>(ei, ei + E, E, NB, cursor, sorted);
        // three LDS-accumulate passes
        k_acc<<<NB, BLK, 0, stream>>>(sorted, base, nullptr, tmp, N, NB);
        k_node1<<<nodeGrid, BLK, 0, stream>>>(x, tmp, dis, g, N);
        k_acc<<<NB, BLK, 0, stream>>>(sorted, base, g, tmp, N, NB);
        k_node2<<<nodeGrid, BLK, 0, stream>>>(g, dis, ab, tmp, g2, N);
        k_acc<<<NB, BLK, 0, stream>>>(sorted, base, g2, tmp, N, NB);
        k_node3<<<nodeGrid, BLK, 0, stream>>>(g2, dis, b2, tmp, out, N);
    } else {
        // fallback: plain-atomic path
        float* fdis = (float*)d_ws;
        float* fg   = fdis + N;
        float* fg2  = fg + N;
        float* ftmp = fg2 + N;
        float* fab  = ftmp + N;
        const int eGrid = (E + BLK - 1) / BLK;
        k_ab<<<1, 64, 0, stream>>>(W1, b1, W2, fab, H);
        k_zero_f<<<nodeGrid, BLK, 0, stream>>>(ftmp, N);
        k_deg_fb<<<eGrid, BLK, 0, stream>>>(ei + E, ftmp, E);
        k_node1<<<nodeGrid, BLK, 0, stream>>>(x, ftmp, fdis, fg, N);
        k_zero_f<<<nodeGrid, BLK, 0, stream>>>(ftmp, N);
        k_scat_fb<<<eGrid, BLK, 0, stream>>>(ei, fg, ftmp, E);
        k_node2<<<nodeGrid, BLK, 0, stream>>>(fg, fdis, fab, ftmp, fg2, N);
        k_zero_f<<<nodeGrid, BLK, 0, stream>>>(ftmp, N);
        k_scat_fb<<<eGrid, BLK, 0, stream>>>(ei, fg2, ftmp, E);
        k_node3<<<nodeGrid, BLK, 0, stream>>>(fg2, fdis, b2, ftmp, out, N);
    }
}

// Round 4
// 137.977 us; speedup vs baseline: 3.7613x; 1.0570x over previous
//
#include <hip/hip_runtime.h>
#include <math.h>

// GCN 2-layer on [N,1] collapses to scalar passes:
//   dis[i] = 1/sqrt(1 + indeg[i]);  g[i] = dis[i]*x[i]
//   s[c]   = dis[c]*(g[c] + sum_{e->c} g[row_e])
//   h[i]   = alpha*s[i] + beta   (alpha = W1.W2, beta = b1.W2)
//   g2[i]  = dis[i]*h[i]
//   out[c] = dis[c]*(g2[c] + sum_{e->c} g2[row_e]) + b2
//
// Strategy (r3 finding): counting-sort edges by 2048-node destination chunk
// (CHUNK=2048 -> NB<=64 buckets so k_place write runs are ~1KB: no L2
// write-amplification), then accumulate with LDS atomics only. Each bucket is
// processed by `subs` sub-blocks writing coalesced partials; node kernels
// reduce the partials. Zero global atomics on the per-edge hot paths.

#define CHUNK 2048
#define CHUNK_SHIFT 11
#define PACK_SHIFT 17              // low 17 bits: row (N <= 131072)
#define ROW_MASK ((1u << PACK_SHIFT) - 1u)
#define NBMAX 64

static __device__ __forceinline__ int gid() {
    return blockIdx.x * blockDim.x + threadIdx.x;
}

__global__ void k_zero_i(int* __restrict__ p, int n) {
    int i = gid();
    if (i < n) p[i] = 0;
}

__global__ void k_zero_f(float* __restrict__ p, int n) {
    int i = gid();
    if (i < n) p[i] = 0.0f;
}

// alpha = W1 . W2, beta = b1 . W2  (HIDDEN = 64 = one wave)
__global__ void k_ab(const float* __restrict__ W1, const float* __restrict__ b1,
                     const float* __restrict__ W2, float* __restrict__ ab, int hidden) {
    int t = threadIdx.x;
    float w2 = (t < hidden) ? W2[t] : 0.0f;
    float a = (t < hidden) ? W1[t] * w2 : 0.0f;
    float b = (t < hidden) ? b1[t] * w2 : 0.0f;
    for (int o = 32; o; o >>= 1) {
        a += __shfl_down(a, o);
        b += __shfl_down(b, o);
    }
    if (t == 0) { ab[0] = a; ab[1] = b; }
}

// ---- sort pipeline -------------------------------------------------------

__global__ void k_hist(const int* __restrict__ col, int E, int NB,
                       int* __restrict__ gcount) {
    __shared__ int cnt[NBMAX];
    if (threadIdx.x < NBMAX) cnt[threadIdx.x] = 0;
    __syncthreads();
    int quads = E >> 2;
    int stride = gridDim.x * blockDim.x;
    for (int i = gid(); i < quads; i += stride) {
        int4 c = reinterpret_cast<const int4*>(col)[i];
        atomicAdd(&cnt[c.x >> CHUNK_SHIFT], 1);
        atomicAdd(&cnt[c.y >> CHUNK_SHIFT], 1);
        atomicAdd(&cnt[c.z >> CHUNK_SHIFT], 1);
        atomicAdd(&cnt[c.w >> CHUNK_SHIFT], 1);
    }
    if (blockIdx.x == 0 && threadIdx.x == 0)
        for (int j = quads << 2; j < E; ++j) atomicAdd(&cnt[col[j] >> CHUNK_SHIFT], 1);
    __syncthreads();
    if (threadIdx.x < NB && cnt[threadIdx.x])
        atomicAdd(&gcount[threadIdx.x], cnt[threadIdx.x]);
}

// one wave: exclusive scan over NB <= 64 buckets
__global__ void k_scan64(const int* __restrict__ gcount, int* __restrict__ base,
                         int* __restrict__ cursor, int NB, int E) {
    int t = threadIdx.x;
    int v0 = (t < NB) ? gcount[t] : 0;
    int v = v0;
    for (int off = 1; off < 64; off <<= 1) {
        int u = __shfl_up(v, off);
        if (t >= off) v += u;
    }
    int excl = v - v0;
    if (t < NB) { base[t] = excl; cursor[t] = excl; }
    if (t == 0) base[NB] = E;
}

__global__ void k_place(const int* __restrict__ row, const int* __restrict__ col,
                        int E, int NB, int* __restrict__ cursor,
                        unsigned* __restrict__ sorted) {
    __shared__ int cnt[NBMAX];
    __shared__ int bbase[NBMAX];
    int per = (E + gridDim.x - 1) / gridDim.x;
    int lo = blockIdx.x * per;
    int hi = min(E, lo + per);
    if (threadIdx.x < NBMAX) cnt[threadIdx.x] = 0;
    __syncthreads();
    for (int j = lo + threadIdx.x; j < hi; j += blockDim.x)
        atomicAdd(&cnt[col[j] >> CHUNK_SHIFT], 1);
    __syncthreads();
    if (threadIdx.x < NB) {
        int c = cnt[threadIdx.x];
        bbase[threadIdx.x] = c ? atomicAdd(&cursor[threadIdx.x], c) : 0;
        cnt[threadIdx.x] = 0;
    }
    __syncthreads();
    for (int j = lo + threadIdx.x; j < hi; j += blockDim.x) {
        int c = col[j];
        int b = c >> CHUNK_SHIFT;
        int off = atomicAdd(&cnt[b], 1);
        sorted[bbase[b] + off] =
            (unsigned)row[j] | ((unsigned)(c & (CHUNK - 1)) << PACK_SHIFT);
    }
}

// grid = NB*subs; each sub-block accumulates its slice of bucket b into LDS,
// writes a coalesced per-chunk partial. val==nullptr -> accumulate 1.0 (deg).
__global__ void k_acc(const unsigned* __restrict__ sorted, const int* __restrict__ base,
                      const float* __restrict__ val, float* __restrict__ partial,
                      int subs) {
    __shared__ float acc[CHUNK];
    int b = blockIdx.x / subs;
    int sub = blockIdx.x - b * subs;
    for (int t = threadIdx.x; t < CHUNK; t += blockDim.x) acc[t] = 0.0f;
    __syncthreads();
    int lo = base[b], hi = base[b + 1];
    int len = hi - lo;
    int per = (len + subs - 1) / subs;
    int slo = lo + sub * per;
    int shi = min(hi, slo + per);
    for (int j = slo + threadIdx.x; j < shi; j += blockDim.x) {
        unsigned p = sorted[j];
        float v = val ? val[p & ROW_MASK] : 1.0f;
        atomicAdd(&acc[p >> PACK_SHIFT], v);
    }
    __syncthreads();
    float* dst = partial + (size_t)blockIdx.x * CHUNK;
    for (int t = threadIdx.x; t < CHUNK; t += blockDim.x) dst[t] = acc[t];
}

// ---- node-wise passes (also reduce the `subs` partials) ------------------

__global__ void k_node1(const float* __restrict__ x, const float* __restrict__ partial,
                        int subs, float* __restrict__ dis, float* __restrict__ g, int N) {
    int i = gid();
    if (i >= N) return;
    const float* p = partial + ((size_t)(i >> CHUNK_SHIFT) * subs) * CHUNK + (i & (CHUNK - 1));
    float t = 1.0f;  // self-loop
    for (int s = 0; s < subs; ++s) t += p[(size_t)s * CHUNK];
    float d = rsqrtf(t);
    dis[i] = d;
    g[i] = d * x[i];
}

__global__ void k_node2(const float* __restrict__ g, const float* __restrict__ dis,
                        const float* __restrict__ ab, const float* __restrict__ partial,
                        int subs, float* __restrict__ g2, int N) {
    int i = gid();
    if (i >= N) return;
    const float* p = partial + ((size_t)(i >> CHUNK_SHIFT) * subs) * CHUNK + (i & (CHUNK - 1));
    float t = g[i];
    for (int s = 0; s < subs; ++s) t += p[(size_t)s * CHUNK];
    float sv = dis[i] * t;
    float h = ab[0] * sv + ab[1];
    g2[i] = dis[i] * h;
}

__global__ void k_node3(const float* __restrict__ g2, const float* __restrict__ dis,
                        const float* __restrict__ b2, const float* __restrict__ partial,
                        int subs, float* __restrict__ out, int N) {
    int i = gid();
    if (i >= N) return;
    const float* p = partial + ((size_t)(i >> CHUNK_SHIFT) * subs) * CHUNK + (i & (CHUNK - 1));
    float t = g2[i];
    for (int s = 0; s < subs; ++s) t += p[(size_t)s * CHUNK];
    out[i] = dis[i] * t + b2[0];
}

// ---- fallback (plain device atomics, known-correct) ----------------------

__global__ void k_deg_fb(const int* __restrict__ col, float* __restrict__ t, int E) {
    int i = gid();
    if (i < E) atomicAdd(&t[col[i]], 1.0f);
}

__global__ void k_scat_fb(const int* __restrict__ ei, const float* __restrict__ val,
                          float* __restrict__ t, int E) {
    int i = gid();
    if (i < E) atomicAdd(&t[ei[E + i]], val[ei[i]]);
}

__global__ void k_node1_fb(const float* __restrict__ x, const float* __restrict__ degsum,
                           float* __restrict__ dis, float* __restrict__ g, int N) {
    int i = gid();
    if (i < N) {
        float d = rsqrtf(1.0f + degsum[i]);
        dis[i] = d;
        g[i] = d * x[i];
    }
}

__global__ void k_node2_fb(const float* __restrict__ g, const float* __restrict__ dis,
                           const float* __restrict__ ab, const float* __restrict__ sum1,
                           float* __restrict__ g2, int N) {
    int i = gid();
    if (i < N) {
        float s = dis[i] * (g[i] + sum1[i]);
        g2[i] = dis[i] * (ab[0] * s + ab[1]);
    }
}

__global__ void k_node3_fb(const float* __restrict__ g2, const float* __restrict__ dis,
                           const float* __restrict__ b2, const float* __restrict__ sum2,
                           float* __restrict__ out, int N) {
    int i = gid();
    if (i < N) out[i] = dis[i] * (g2[i] + sum2[i]) + b2[0];
}

extern "C" void kernel_launch(void* const* d_in, const int* in_sizes, int n_in,
                              void* d_out, int out_size, void* d_ws, size_t ws_size,
                              hipStream_t stream) {
    const float* x  = (const float*)d_in[0];
    const int*   ei = (const int*)d_in[1];
    const float* W1 = (const float*)d_in[2];
    const float* b1 = (const float*)d_in[3];
    const float* W2 = (const float*)d_in[4];
    const float* b2 = (const float*)d_in[5];
    float* out = (float*)d_out;

    const int N = in_sizes[0];       // 100000
    const int E = in_sizes[1] / 2;   // 3200000
    const int H = in_sizes[2];       // 64
    const int NB = (N + CHUNK - 1) >> CHUNK_SHIFT;

    const int BLK = 256;
    const int nodeGrid = (N + BLK - 1) / BLK;

    // workspace layout (fixed part)
    char* w = (char*)d_ws;
    unsigned* sorted = (unsigned*)w;   w += (size_t)E * 4;
    float* dis = (float*)w;            w += (size_t)N * 4;
    float* g   = (float*)w;            w += (size_t)N * 4;
    float* g2  = (float*)w;            w += (size_t)N * 4;
    int* gcount = (int*)w;             w += NBMAX * 4;
    int* base   = (int*)w;             w += (NBMAX + 1) * 4;
    int* cursor = (int*)w;             w += NBMAX * 4;
    float* ab   = (float*)w;           w += 2 * 4;
    float* partial = (float*)w;        // [NB * subs * CHUNK]
    size_t fixed = (size_t)(w - (char*)d_ws);

    // pick subs (sub-blocks per bucket) from remaining workspace, target 16
    long long avail = (long long)ws_size - (long long)fixed;
    long long per_sub = (long long)NB * CHUNK * 4;
    int subs = (avail > 0 && per_sub > 0) ? (int)(avail / per_sub) : 0;
    if (subs > 16) subs = 16;

    if (N <= (1 << PACK_SHIFT) && NB <= NBMAX && subs >= 1) {
        const int accGrid = NB * subs;
        k_zero_i<<<1, NBMAX, 0, stream>>>(gcount, NBMAX);
        k_ab<<<1, 64, 0, stream>>>(W1, b1, W2, ab, H);
        k_hist<<<256, 256, 0, stream>>>(ei + E, E, NB, gcount);
        k_scan64<<<1, 64, 0, stream>>>(gcount, base, cursor, NB, E);
        k_place<<<256, 512, 0, stream>>>(ei, ei + E, E, NB, cursor, sorted);
        k_acc<<<accGrid, 512, 0, stream>>>(sorted, base, nullptr, partial, subs);
        k_node1<<<nodeGrid, BLK, 0, stream>>>(x, partial, subs, dis, g, N);
        k_acc<<<accGrid, 512, 0, stream>>>(sorted, base, g, partial, subs);
        k_node2<<<nodeGrid, BLK, 0, stream>>>(g, dis, ab, partial, subs, g2, N);
        k_acc<<<accGrid, 512, 0, stream>>>(sorted, base, g2, partial, subs);
        k_node3<<<nodeGrid, BLK, 0, stream>>>(g2, dis, b2, partial, subs, out, N);
    } else {
        // fallback: plain-atomic path (slow but correct)
        float* fdis = (float*)d_ws;
        float* fg   = fdis + N;
        float* fg2  = fg + N;
        float* ftmp = fg2 + N;
        float* fab  = ftmp + N;
        const int eGrid = (E + BLK - 1) / BLK;
        k_ab<<<1, 64, 0, stream>>>(W1, b1, W2, fab, H);
        k_zero_f<<<nodeGrid, BLK, 0, stream>>>(ftmp, N);
        k_deg_fb<<<eGrid, BLK, 0, stream>>>(ei + E, ftmp, E);
        k_node1_fb<<<nodeGrid, BLK, 0, stream>>>(x, ftmp, fdis, fg, N);
        k_zero_f<<<nodeGrid, BLK, 0, stream>>>(ftmp, N);
        k_scat_fb<<<eGrid, BLK, 0, stream>>>(ei, fg, ftmp, E);
        k_node2_fb<<<nodeGrid, BLK, 0, stream>>>(fg, fdis, fab, ftmp, fg2, N);
        k_zero_f<<<nodeGrid, BLK, 0, stream>>>(ftmp, N);
        k_scat_fb<<<eGrid, BLK, 0, stream>>>(ei, fg2, ftmp, E);
        k_node3_fb<<<nodeGrid, BLK, 0, stream>>>(fg2, fdis, b2, ftmp, out, N);
    }
}